// Round 5
// baseline (342.210 us; speedup 1.0000x reference)
//
#include <hip/hip_runtime.h>

typedef __bf16 bf16;
typedef __bf16 bf16x4 __attribute__((ext_vector_type(4)));
typedef __bf16 bf16x8 __attribute__((ext_vector_type(8)));
typedef float  f32x2  __attribute__((ext_vector_type(2)));
typedef float  f32x4  __attribute__((ext_vector_type(4)));
typedef unsigned int u32;
typedef u32 u32x2 __attribute__((ext_vector_type(2)));
typedef u32 u32x4 __attribute__((ext_vector_type(4)));
typedef unsigned short u16;

#define NJ 75
#define SA 104   // A_lds stride (bf16), rows 16B-aligned, ~2-way banks
#define SH 104   // h1 [c:128][j:96pad]
#define SG 136   // gss [j:80][c:128pad]
#define SX 104   // xT [4][96pad]
#define SR 88    // reds [w:8][j:88] f32x2
#define LN_EPS 1e-5f
#define MFMA16(a,b,c) __builtin_amdgcn_mfma_f32_16x16x32_bf16((a),(b),(c),0,0,0)

static __device__ __forceinline__ f32x4 f4z(){ f32x4 v={0.f,0.f,0.f,0.f}; return v; }
static __device__ __forceinline__ float bperm(int srcLane, float v){
  return __int_as_float(__builtin_amdgcn_ds_bpermute(srcLane<<2, __float_as_int(v)));
}
static __device__ __forceinline__ u32 pk2(float a, float b){
  u32 ua = (u32)__builtin_bit_cast(u16,(bf16)a);
  u32 ub = (u32)__builtin_bit_cast(u16,(bf16)b);
  return ua | (ub<<16);
}
static __device__ __forceinline__ float lo16f(u32 u){ return __uint_as_float(u<<16); }
static __device__ __forceinline__ float hi16f(u32 u){ return __uint_as_float(u & 0xffff0000u); }

__global__ __launch_bounds__(512, 4)
void ke4(const float* __restrict__ gx,  const float* __restrict__ gA,
         const float* __restrict__ gW1, const float* __restrict__ gg1, const float* __restrict__ gb1,
         const float* __restrict__ gW2, const float* __restrict__ gg2, const float* __restrict__ gb2,
         const float* __restrict__ gWp, const float* __restrict__ gbp,
         float* __restrict__ gout, int B)
{
  __shared__ __align__(16) bf16 A_lds[80*SA];   // 16,640 B  [j][k] (symmetric)
  __shared__ __align__(16) bf16 h1[128*SH];     // 26,624 B  [c][j]
  __shared__ __align__(16) bf16 gss[80*SG];     // 21,760 B  [j][c]
  __shared__ __align__(16) bf16 xT[4*SX];       //    832 B  [coord][j]
  __shared__ __align__(16) float reds[8*SR*2];  //  5,632 B  [w][j](s,q)
  __shared__ __align__(16) float skl[2][256];   //  2,048 B
  __shared__ __align__(16) u32  g1b1[128];      //    512 B
  __shared__ __align__(16) u32  g2b2[256];      //  1,024 B
  __shared__ __align__(16) bf16 W1l[128*4];     //  1,024 B
  __shared__ float xbars[4];

  const int tid = threadIdx.x;
  const int w   = tid >> 6;
  const int l   = tid & 63;
  const int l16 = l & 15;
  const int lg  = l >> 4;

  // ---------------- one-time init ----------------
  for (int i = tid; i < 80*SA; i += 512) {
    const int r = i / SA, c = i - r*SA;
    A_lds[i] = (bf16)((r < NJ && c < NJ) ? gA[r*NJ + c] : 0.f);
  }
  for (int i = tid; i < 128*SH; i += 512) h1[i] = (bf16)0.f;
  for (int i = tid; i < 4*SX;   i += 512) xT[i] = (bf16)0.f;
  if (tid < 128) {
    g1b1[tid] = pk2(gg1[tid], gb1[tid]);
    W1l[tid*4+0] = (bf16)gW1[tid*3+0];
    W1l[tid*4+1] = (bf16)gW1[tid*3+1];
    W1l[tid*4+2] = (bf16)gW1[tid*3+2];
    W1l[tid*4+3] = (bf16)0.f;
  }
  if (tid < 256) g2b2[tid] = pk2(gg2[tid], gb2[tid]);

  // persistent W2 fragments: wave owns o in [32w, 32w+32)
  bf16x8 W2fr[2][4];
  #pragma unroll
  for (int ot = 0; ot < 2; ++ot) {
    const int o = 16*(2*w + ot) + l16;
    #pragma unroll
    for (int ks = 0; ks < 4; ++ks) {
      bf16x8 v;
      #pragma unroll
      for (int e = 0; e < 8; ++e) v[e] = (bf16)gW2[o*128 + 32*ks + 8*lg + e];
      W2fr[ot][ks] = v;
    }
  }
  __syncthreads();

  const int  fpb  = (B + 511) >> 9;          // grid = 512
  const long base = (long)blockIdx.x * fpb;

  u32x2 pz[5][2];   // packed bf16 z (frame i-1), carried P2 -> next P1
  #pragma unroll
  for (int jt = 0; jt < 5; ++jt) { pz[jt][0] = (u32x2){0,0}; pz[jt][1] = (u32x2){0,0}; }

  const int nint = fpb + 2;
  for (int i = 0; i < nint; ++i) {
    // ==================== P1 ====================
    // S_B(i-1): g = A h1'  (c-slice = wave)
    if (i >= 1 && i <= fpb) {
      const bf16* hb = &h1[(16*w + l16)*SH];
      bf16x8 hf0 = *(const bf16x8*)&hb[ 0 + 8*lg];
      bf16x8 hf1 = *(const bf16x8*)&hb[32 + 8*lg];
      bf16x8 hf2 = *(const bf16x8*)&hb[64 + 8*lg];
      #pragma unroll
      for (int jt = 0; jt < 5; ++jt) {
        const bf16* ab = &A_lds[(16*jt + l16)*SA + 8*lg];
        f32x4 ag = f4z();
        ag = MFMA16(hf0, *(const bf16x8*)&ab[ 0], ag);
        ag = MFMA16(hf1, *(const bf16x8*)&ab[32], ag);
        ag = MFMA16(hf2, *(const bf16x8*)&ab[64], ag);
        bf16x4 p;
        #pragma unroll
        for (int r = 0; r < 4; ++r) p[r] = (bf16)ag[r];
        *(bf16x4*)&gss[(16*jt + l16)*SG + 16*w + 4*lg] = p;
      }
    }
    // S_D(i-2): LN2 finalize + apply + mean + skip + store
    if (i >= 2) {
      float S = 0.f, Q = 0.f, S2 = 0.f, Q2 = 0.f;
      #pragma unroll
      for (int ww = 0; ww < 8; ++ww) {
        const f32x2 a = *(const f32x2*)&reds[(ww*SR + l)*2];
        const f32x2 b = *(const f32x2*)&reds[(ww*SR + 64 + l16)*2];
        S += a[0]; Q += a[1]; S2 += b[0]; Q2 += b[1];
      }
      const float mu  = S * (1.f/256.f);
      const float rs  = rsqrtf(Q * (1.f/256.f) - mu*mu + LN_EPS);
      const float nm  = -mu * rs;
      const float mu2 = S2 * (1.f/256.f);
      const float rs2 = rsqrtf(Q2 * (1.f/256.f) - mu2*mu2 + LN_EPS);
      const float nm2 = -mu2 * rs2;
      float rsv[5], nmv[5];
      #pragma unroll
      for (int jt = 0; jt < 4; ++jt) {
        rsv[jt] = bperm(16*jt + l16, rs);
        nmv[jt] = bperm(16*jt + l16, nm);
      }
      rsv[4] = rs2; nmv[4] = nm2;
      float os[2][4];
      #pragma unroll
      for (int ot = 0; ot < 2; ++ot) {
        const u32x4 gb = *(const u32x4*)&g2b2[16*(2*w + ot) + 4*lg];
        #pragma unroll
        for (int r = 0; r < 4; ++r) os[ot][r] = 0.f;
        #pragma unroll
        for (int jt = 0; jt < 5; ++jt) {
          const u32x2 pzz = pz[jt][ot];
          float zv[4];
          zv[0] = lo16f(pzz[0]); zv[1] = hi16f(pzz[0]);
          zv[2] = lo16f(pzz[1]); zv[3] = hi16f(pzz[1]);
          #pragma unroll
          for (int r = 0; r < 4; ++r) {
            float v = fmaf(fmaf(zv[r], rsv[jt], nmv[jt]), lo16f(gb[r]), hi16f(gb[r]));
            v = fmaxf(v, 0.f);
            if (jt == 4) v = (l16 < 11) ? v : 0.f;
            os[ot][r] += v;
          }
        }
      }
      #pragma unroll
      for (int m = 8; m >= 1; m >>= 1)
        #pragma unroll
        for (int ot = 0; ot < 2; ++ot)
          #pragma unroll
          for (int r = 0; r < 4; ++r) os[ot][r] += __shfl_xor(os[ot][r], m);
      const long f = base + (i - 2);
      if (l16 == 0 && f < B) {
        #pragma unroll
        for (int ot = 0; ot < 2; ++ot) {
          const int o0 = 16*(2*w + ot) + 4*lg;
          const f32x4 sk = *(const f32x4*)&skl[(i-2)&1][o0];
          f32x4 res;
          #pragma unroll
          for (int r = 0; r < 4; ++r) res[r] = os[ot][r]*(1.f/NJ) + sk[r];
          *(f32x4*)&gout[f*256 + o0] = res;
        }
      }
    }
    // stage x(i) (wave 5)
    if (w == 5 && i < fpb) {
      long f = base + i; if (f >= B) f = B - 1;
      #pragma unroll
      for (int k = 0; k < 4; ++k) {
        const int t = l + 64*k;
        if (t < 225) {
          const float v = gx[f*225 + t];
          const int j = (t*21846) >> 16;   // t/3
          const int co = t - 3*j;
          xT[co*SX + j] = (bf16)v;
        }
      }
      #pragma unroll
      for (int k = 0; k < 3; ++k) {
        float s = (float)xT[k*SX + l];
        if (l < 16) s += (float)xT[k*SX + 64 + l];
        #pragma unroll
        for (int m = 32; m >= 1; m >>= 1) s += __shfl_xor(s, m);
        if (l == 0) xbars[k] = s * (1.f/NJ);
      }
    }
    __syncthreads();

    // ==================== P2 ====================
    // S_A(i): x -> h1' (waves 0-4, j-tile = w)
    if (i < fpb && w < 5) {
      const int xrow = (l16 < 3) ? l16 : 3;
      const bf16* xb = &xT[xrow*SX + 8*lg];
      const bf16* ab = &A_lds[(16*w + l16)*SA + 8*lg];
      f32x4 at = f4z();
      at = MFMA16(*(const bf16x8*)&xb[ 0], *(const bf16x8*)&ab[ 0], at);
      at = MFMA16(*(const bf16x8*)&xb[32], *(const bf16x8*)&ab[32], at);
      at = MFMA16(*(const bf16x8*)&xb[64], *(const bf16x8*)&ab[64], at);
      const float a0 = (lg == 0) ? at[0] : 0.f;
      const float a1 = (lg == 0) ? at[1] : 0.f;
      const float a2 = (lg == 0) ? at[2] : 0.f;
      bf16x8 hA;
      #pragma unroll
      for (int e = 0; e < 8; ++e) hA[e] = (bf16)0.f;
      hA[0] = (bf16)a0; hA[1] = (bf16)a1; hA[2] = (bf16)a2;
      f32x4 hp[8];
      float s[4] = {0.f,0.f,0.f,0.f}, q[4] = {0.f,0.f,0.f,0.f};
      #pragma unroll
      for (int nt = 0; nt < 8; ++nt) {
        const bf16x4 w4 = *(const bf16x4*)&W1l[(16*nt + l16)*4];
        bf16x8 wb;
        wb[0] = w4[0]; wb[1] = w4[1]; wb[2] = w4[2]; wb[3] = w4[3];
        wb[4] = w4[3]; wb[5] = w4[3]; wb[6] = w4[3]; wb[7] = w4[3];
        hp[nt] = MFMA16(hA, wb, f4z());
        #pragma unroll
        for (int r = 0; r < 4; ++r) { s[r] += hp[nt][r]; q[r] = fmaf(hp[nt][r], hp[nt][r], q[r]); }
      }
      #pragma unroll
      for (int m = 1; m <= 8; m <<= 1)
        #pragma unroll
        for (int r = 0; r < 4; ++r) { s[r] += __shfl_xor(s[r], m); q[r] += __shfl_xor(q[r], m); }
      float rsq[4], nmq[4];
      #pragma unroll
      for (int r = 0; r < 4; ++r) {
        const float mu = s[r] * (1.f/128.f);
        rsq[r] = rsqrtf(q[r] * (1.f/128.f) - mu*mu + LN_EPS);
        nmq[r] = -mu * rsq[r];
      }
      #pragma unroll
      for (int nt = 0; nt < 8; ++nt) {
        const u32 gb = g1b1[16*nt + l16];
        const float gam = lo16f(gb), bet = hi16f(gb);
        bf16x4 pkk;
        #pragma unroll
        for (int r = 0; r < 4; ++r) {
          float v = fmaf(fmaf(hp[nt][r], rsq[r], nmq[r]), gam, bet);
          pkk[r] = (bf16)fmaxf(v, 0.f);
        }
        *(bf16x4*)&h1[(16*nt + l16)*SH + 16*w + 4*lg] = pkk;
      }
    }
    // S_C(i-1): z = W2 g^T (o-slice = wave), stats -> reds, pack -> pz
    if (i >= 1 && i <= fpb) {
      #pragma unroll
      for (int jt = 0; jt < 5; ++jt) {
        const bf16* gr = &gss[(16*jt + l16)*SG + 8*lg];
        f32x4 z0 = f4z(), z1 = f4z();
        #pragma unroll
        for (int ks = 0; ks < 4; ++ks) {
          const bf16x8 gf = *(const bf16x8*)&gr[32*ks];
          z0 = MFMA16(W2fr[0][ks], gf, z0);
          z1 = MFMA16(W2fr[1][ks], gf, z1);
        }
        float s = 0.f, q = 0.f;
        #pragma unroll
        for (int r = 0; r < 4; ++r) {
          s += z0[r] + z1[r];
          q = fmaf(z0[r], z0[r], q); q = fmaf(z1[r], z1[r], q);
        }
        s += __shfl_xor(s, 16); q += __shfl_xor(q, 16);
        s += __shfl_xor(s, 32); q += __shfl_xor(q, 32);
        if (lg == 0) { f32x2 sq = {s, q}; *(f32x2*)&reds[(w*SR + 16*jt + l16)*2] = sq; }
        pz[jt][0] = (u32x2){ pk2(z0[0], z0[1]), pk2(z0[2], z0[3]) };
        pz[jt][1] = (u32x2){ pk2(z1[0], z1[1]), pk2(z1[2], z1[3]) };
      }
    }
    // skip(i) (wave 6)
    if (w == 6 && i < fpb) {
      const float xb0 = xbars[0], xb1 = xbars[1], xb2 = xbars[2];
      #pragma unroll
      for (int k = 0; k < 4; ++k) {
        const int o = l + 64*k;
        skl[i&1][o] = gbp[o] + gWp[o*3]*xb0 + gWp[o*3+1]*xb1 + gWp[o*3+2]*xb2;
      }
    }
    __syncthreads();
  }
}

extern "C" void kernel_launch(void* const* d_in, const int* in_sizes, int n_in,
                              void* d_out, int out_size, void* d_ws, size_t ws_size,
                              hipStream_t stream) {
  const float* x  = (const float*)d_in[0];
  const float* A  = (const float*)d_in[1];
  const float* W1 = (const float*)d_in[2];
  const float* g1 = (const float*)d_in[3];
  const float* b1 = (const float*)d_in[4];
  const float* W2 = (const float*)d_in[5];
  const float* g2 = (const float*)d_in[6];
  const float* b2 = (const float*)d_in[7];
  const float* Wp = (const float*)d_in[8];
  const float* bp = (const float*)d_in[9];
  float* out = (float*)d_out;
  const int B = in_sizes[0] / 225;
  ke4<<<dim3(512), dim3(512), 0, stream>>>(x, A, W1, g1, b1, W2, g2, b2, Wp, bp, out, B);
}

// Round 6
// 303.319 us; speedup vs baseline: 1.1282x; 1.1282x over previous
//
#include <hip/hip_runtime.h>

typedef __bf16 bf16;
typedef __bf16 bf16x4 __attribute__((ext_vector_type(4)));
typedef __bf16 bf16x8 __attribute__((ext_vector_type(8)));
typedef float  f32x2  __attribute__((ext_vector_type(2)));
typedef float  f32x4  __attribute__((ext_vector_type(4)));
typedef unsigned int u32;
typedef u32 u32x2 __attribute__((ext_vector_type(2)));
typedef u32 u32x4 __attribute__((ext_vector_type(4)));
typedef unsigned short u16;

#define NJ 75
#define SA 104      // A_lds stride (bf16)
#define SH 104      // h1 stride (bf16)
#define SG 128      // gss stride (bf16): 256B rows, XOR-swizzled
#define SX 104      // xT stride
#define SR 88       // reds [w][j] f32x2
#define LN_EPS 1e-5f
#define MFMA16(a,b,c) __builtin_amdgcn_mfma_f32_16x16x32_bf16((a),(b),(c),0,0,0)

static __device__ __forceinline__ f32x4 f4z(){ f32x4 v={0.f,0.f,0.f,0.f}; return v; }
static __device__ __forceinline__ u32 pk2(float a, float b){
  u32 ua = (u32)__builtin_bit_cast(u16,(bf16)a);
  u32 ub = (u32)__builtin_bit_cast(u16,(bf16)b);
  return ua | (ub<<16);
}
static __device__ __forceinline__ float lo16f(u32 u){ return __uint_as_float(u<<16); }
static __device__ __forceinline__ float hi16f(u32 u){ return __uint_as_float(u & 0xffff0000u); }

template<int C>
static __device__ __forceinline__ float dppterm(float v){
  return __int_as_float(__builtin_amdgcn_update_dpp(0, __float_as_int(v), C, 0xF, 0xF, true));
}
// all-lanes sum over each 16-lane row: xor1, xor2, half_mirror, mirror
static __device__ __forceinline__ float red16(float v){
  v += dppterm<0xB1>(v);
  v += dppterm<0x4E>(v);
  v += dppterm<0x141>(v);
  v += dppterm<0x140>(v);
  return v;
}

__global__ __launch_bounds__(512, 4)
void ke5(const float* __restrict__ gx,  const float* __restrict__ gA,
         const float* __restrict__ gW1, const float* __restrict__ gg1, const float* __restrict__ gb1,
         const float* __restrict__ gW2, const float* __restrict__ gg2, const float* __restrict__ gb2,
         const float* __restrict__ gWp, const float* __restrict__ gbp,
         float* __restrict__ gout, int B)
{
  __shared__ __align__(16) bf16 A_lds[80*SA];   // 16,640 B
  __shared__ __align__(16) bf16 h1[128*SH];     // 26,624 B
  __shared__ __align__(16) bf16 gss[80*SG];     // 20,480 B (swizzled)
  __shared__ __align__(16) bf16 xT[4*SX];       //    832 B
  __shared__ __align__(16) float reds[8*SR*2];  //  5,632 B
  __shared__ __align__(16) float fin[80*2];     //    640 B (nm, rs)
  __shared__ __align__(16) float skl[4][256];   //  4,096 B
  __shared__ __align__(16) u32  g1b1[128];      //    512 B
  __shared__ __align__(16) u32  g2b2[256];      //  1,024 B
  __shared__ __align__(16) bf16 W1l[128*4];     //  1,024 B
  __shared__ __align__(16) u32x2 wpl[256];      //  2,048 B
  __shared__ float xbars[4];

  const int tid = threadIdx.x;
  const int w   = tid >> 6;
  const int l   = tid & 63;
  const int l16 = l & 15;
  const int lg  = l >> 4;

  // ---------------- one-time init ----------------
  for (int i = tid; i < 80*SA; i += 512) {
    const int r = i / SA, c = i - r*SA;
    A_lds[i] = (bf16)((r < NJ && c < NJ) ? gA[r*NJ + c] : 0.f);
  }
  for (int i = tid; i < 128*SH; i += 512) h1[i] = (bf16)0.f;
  for (int i = tid; i < 4*SX;   i += 512) xT[i] = (bf16)0.f;
  if (tid < 128) {
    g1b1[tid] = pk2(gg1[tid], gb1[tid]);
    W1l[tid*4+0] = (bf16)gW1[tid*3+0];
    W1l[tid*4+1] = (bf16)gW1[tid*3+1];
    W1l[tid*4+2] = (bf16)gW1[tid*3+2];
    W1l[tid*4+3] = (bf16)0.f;
  }
  if (tid < 256) {
    g2b2[tid] = pk2(gg2[tid], gb2[tid]);
    u32x2 wv = { pk2(gWp[tid*3+0], gWp[tid*3+1]), pk2(gWp[tid*3+2], gbp[tid]) };
    wpl[tid] = wv;
  }

  // persistent W2 fragments: wave owns o in [32w, 32w+32)
  bf16x8 W2fr[2][4];
  #pragma unroll
  for (int ot = 0; ot < 2; ++ot) {
    const int o = 16*(2*w + ot) + l16;
    #pragma unroll
    for (int ks = 0; ks < 4; ++ks) {
      bf16x8 v;
      #pragma unroll
      for (int e = 0; e < 8; ++e) v[e] = (bf16)gW2[o*128 + 32*ks + 8*lg + e];
      W2fr[ot][ks] = v;
    }
  }

  const int  fpb  = (B + 511) >> 9;          // grid = 512
  const long base = (long)blockIdx.x * fpb;

  // prologue: load x(frame base) into regs (wave 5)
  float xv[4] = {0.f, 0.f, 0.f, 0.f};
  if (w == 5) {
    long fg = base; if (fg >= B) fg = B - 1;
    #pragma unroll
    for (int k = 0; k < 4; ++k) { const int t = l + 64*k; if (t < 225) xv[k] = gx[fg*225 + t]; }
  }
  __syncthreads();

  f32x4 zacc[5][2];
  #pragma unroll
  for (int jt = 0; jt < 5; ++jt) { zacc[jt][0] = f4z(); zacc[jt][1] = f4z(); }

  const int nint = fpb + 2;
  for (int i = 0; i < nint; ++i) {
    // ==================== P1 ====================
    // S_B(i-1): g = A h1'  (c-slice = wave), swizzled gss write
    if (i >= 1 && i <= fpb) {
      const bf16* hb = &h1[(16*w + l16)*SH];
      bf16x8 hf0 = *(const bf16x8*)&hb[ 0 + 8*lg];
      bf16x8 hf1 = *(const bf16x8*)&hb[32 + 8*lg];
      bf16x8 hf2 = *(const bf16x8*)&hb[64 + 8*lg];
      const u32 gcol = (u32)((32*w + 8*lg) ^ ((l16 & 7) << 4));
      #pragma unroll
      for (int jt = 0; jt < 5; ++jt) {
        const bf16* ab = &A_lds[(16*jt + l16)*SA + 8*lg];
        f32x4 ag = f4z();
        ag = MFMA16(hf0, *(const bf16x8*)&ab[ 0], ag);
        ag = MFMA16(hf1, *(const bf16x8*)&ab[32], ag);
        ag = MFMA16(hf2, *(const bf16x8*)&ab[64], ag);
        bf16x4 p;
        #pragma unroll
        for (int r = 0; r < 4; ++r) p[r] = (bf16)ag[r];
        *(bf16x4*)((char*)gss + (16*jt + l16)*256 + gcol) = p;
      }
    }
    // wave 5: commit xT(i) from regs + xbar(i)
    if (w == 5 && i < fpb) {
      float s0 = 0.f, s1 = 0.f, s2 = 0.f;
      #pragma unroll
      for (int k = 0; k < 4; ++k) {
        const int t = l + 64*k;
        if (t < 225) {
          const int j = (t*21846) >> 16;   // t/3
          const int co = t - 3*j;
          xT[co*SX + j] = (bf16)xv[k];
          if (co == 0) s0 += xv[k]; else if (co == 1) s1 += xv[k]; else s2 += xv[k];
        }
      }
      s0 = red16(s0); s0 += __shfl_xor(s0, 16); s0 += __shfl_xor(s0, 32);
      s1 = red16(s1); s1 += __shfl_xor(s1, 16); s1 += __shfl_xor(s1, 32);
      s2 = red16(s2); s2 += __shfl_xor(s2, 16); s2 += __shfl_xor(s2, 32);
      if (l == 0) { xbars[0] = s0*(1.f/NJ); xbars[1] = s1*(1.f/NJ); xbars[2] = s2*(1.f/NJ); }
    }
    // wave 6: finalize LN2 stats for frame i-2: reds -> fin
    if (w == 6 && i >= 2) {
      {
        const int j1 = l;
        float S = 0.f, Q = 0.f;
        #pragma unroll
        for (int ww = 0; ww < 8; ++ww) {
          const f32x2 a = *(const f32x2*)&reds[(ww*SR + j1)*2];
          S += a[0]; Q += a[1];
        }
        const float mu = S * (1.f/256.f);
        const float rs = rsqrtf(Q * (1.f/256.f) - mu*mu + LN_EPS);
        f32x2 nr = { -mu*rs, rs };
        *(f32x2*)&fin[j1*2] = nr;
      }
      if (l < 16) {
        const int j2 = 64 + l;
        float S = 0.f, Q = 0.f;
        #pragma unroll
        for (int ww = 0; ww < 8; ++ww) {
          const f32x2 a = *(const f32x2*)&reds[(ww*SR + j2)*2];
          S += a[0]; Q += a[1];
        }
        const float mu = S * (1.f/256.f);
        const float rs = rsqrtf(Q * (1.f/256.f) - mu*mu + LN_EPS);
        f32x2 nr = { -mu*rs, rs };
        *(f32x2*)&fin[j2*2] = nr;
      }
    }
    __syncthreads();

    // ==================== P2 ====================
    // S_D(i-2): LN2 apply + mean + skip + store (consumes zacc, fin)
    if (i >= 2) {
      float nmv[5], rsv[5];
      #pragma unroll
      for (int jt = 0; jt < 5; ++jt) {
        const f32x2 nr = *(const f32x2*)&fin[(16*jt + l16)*2];
        nmv[jt] = nr[0]; rsv[jt] = nr[1];
      }
      float os[2][4];
      #pragma unroll
      for (int ot = 0; ot < 2; ++ot) {
        const u32x4 gb = *(const u32x4*)&g2b2[16*(2*w + ot) + 4*lg];
        #pragma unroll
        for (int r = 0; r < 4; ++r) os[ot][r] = 0.f;
        #pragma unroll
        for (int jt = 0; jt < 5; ++jt) {
          #pragma unroll
          for (int r = 0; r < 4; ++r) {
            float v = fmaf(fmaf(zacc[jt][ot][r], rsv[jt], nmv[jt]), lo16f(gb[r]), hi16f(gb[r]));
            v = fmaxf(v, 0.f);
            if (jt == 4) v = (l16 < 11) ? v : 0.f;
            os[ot][r] += v;
          }
        }
        #pragma unroll
        for (int r = 0; r < 4; ++r) os[ot][r] = red16(os[ot][r]);
      }
      const long f = base + (i - 2);
      if (l16 == 0 && f < B) {
        #pragma unroll
        for (int ot = 0; ot < 2; ++ot) {
          const int o0 = 16*(2*w + ot) + 4*lg;
          const f32x4 sk = *(const f32x4*)&skl[(i-2)&3][o0];
          f32x4 res;
          #pragma unroll
          for (int r = 0; r < 4; ++r) res[r] = os[ot][r]*(1.f/NJ) + sk[r];
          *(f32x4*)&gout[f*256 + o0] = res;
        }
      }
    }
    // S_C(i-1): z = W2 g^T (o-slice = wave) + partial stats
    if (i >= 1 && i <= fpb) {
      const u32 sw = (u32)((l16 & 7) << 4);
      #pragma unroll
      for (int jt = 0; jt < 5; ++jt) {
        const char* gbase = (const char*)gss + (16*jt + l16)*256;
        f32x4 z0 = f4z(), z1 = f4z();
        #pragma unroll
        for (int ks = 0; ks < 4; ++ks) {
          const bf16x8 gf = *(const bf16x8*)(gbase + (((u32)(64*ks + 16*lg)) ^ sw));
          z0 = MFMA16(W2fr[0][ks], gf, z0);
          z1 = MFMA16(W2fr[1][ks], gf, z1);
        }
        float s = 0.f, q = 0.f;
        #pragma unroll
        for (int r = 0; r < 4; ++r) {
          s += z0[r] + z1[r];
          q = fmaf(z0[r], z0[r], q); q = fmaf(z1[r], z1[r], q);
        }
        s += __shfl_xor(s, 16); q += __shfl_xor(q, 16);
        s += __shfl_xor(s, 32); q += __shfl_xor(q, 32);
        if (lg == 0) { f32x2 sq = {s, q}; *(f32x2*)&reds[(w*SR + 16*jt + l16)*2] = sq; }
        zacc[jt][0] = z0; zacc[jt][1] = z1;
      }
    }
    // S_A(i): x -> h1' (waves 0-4, j-tile = w)
    if (i < fpb && w < 5) {
      const int xrow = (l16 < 3) ? l16 : 3;
      const bf16* xb = &xT[xrow*SX + 8*lg];
      const bf16* ab = &A_lds[(16*w + l16)*SA + 8*lg];
      f32x4 at = f4z();
      at = MFMA16(*(const bf16x8*)&xb[ 0], *(const bf16x8*)&ab[ 0], at);
      at = MFMA16(*(const bf16x8*)&xb[32], *(const bf16x8*)&ab[32], at);
      at = MFMA16(*(const bf16x8*)&xb[64], *(const bf16x8*)&ab[64], at);
      const float a0 = (lg == 0) ? at[0] : 0.f;
      const float a1 = (lg == 0) ? at[1] : 0.f;
      const float a2 = (lg == 0) ? at[2] : 0.f;
      bf16x8 hA;
      #pragma unroll
      for (int e = 0; e < 8; ++e) hA[e] = (bf16)0.f;
      hA[0] = (bf16)a0; hA[1] = (bf16)a1; hA[2] = (bf16)a2;
      f32x4 hp[8];
      float s[4] = {0.f,0.f,0.f,0.f}, q[4] = {0.f,0.f,0.f,0.f};
      #pragma unroll
      for (int nt = 0; nt < 8; ++nt) {
        const bf16x4 w4 = *(const bf16x4*)&W1l[(16*nt + l16)*4];
        bf16x8 wb;
        wb[0] = w4[0]; wb[1] = w4[1]; wb[2] = w4[2]; wb[3] = w4[3];
        wb[4] = w4[3]; wb[5] = w4[3]; wb[6] = w4[3]; wb[7] = w4[3];
        hp[nt] = MFMA16(hA, wb, f4z());
        #pragma unroll
        for (int r = 0; r < 4; ++r) { s[r] += hp[nt][r]; q[r] = fmaf(hp[nt][r], hp[nt][r], q[r]); }
      }
      #pragma unroll
      for (int r = 0; r < 4; ++r) { s[r] = red16(s[r]); q[r] = red16(q[r]); }
      float rsq[4], nmq[4];
      #pragma unroll
      for (int r = 0; r < 4; ++r) {
        const float mu = s[r] * (1.f/128.f);
        rsq[r] = rsqrtf(q[r] * (1.f/128.f) - mu*mu + LN_EPS);
        nmq[r] = -mu * rsq[r];
      }
      #pragma unroll
      for (int nt = 0; nt < 8; ++nt) {
        const u32 gb = g1b1[16*nt + l16];
        const float gam = lo16f(gb), bet = hi16f(gb);
        bf16x4 pkk;
        #pragma unroll
        for (int r = 0; r < 4; ++r) {
          float v = fmaf(fmaf(hp[nt][r], rsq[r], nmq[r]), gam, bet);
          pkk[r] = (bf16)fmaxf(v, 0.f);
        }
        *(bf16x4*)&h1[(16*nt + l16)*SH + 16*w + 4*lg] = pkk;
      }
    }
    // wave 5: issue x(i+1) loads (drain covered by long P2)
    if (w == 5 && i + 1 < fpb) {
      long fg = base + i + 1; if (fg >= B) fg = B - 1;
      #pragma unroll
      for (int k = 0; k < 4; ++k) { const int t = l + 64*k; if (t < 225) xv[k] = gx[fg*225 + t]; }
    }
    // wave 6: skip(i)
    if (w == 6 && i < fpb) {
      const float xb0 = xbars[0], xb1 = xbars[1], xb2 = xbars[2];
      #pragma unroll
      for (int k = 0; k < 4; ++k) {
        const int o = l + 64*k;
        const u32x2 wv = wpl[o];
        skl[i&3][o] = fmaf(lo16f(wv[0]), xb0, fmaf(hi16f(wv[0]), xb1, fmaf(lo16f(wv[1]), xb2, hi16f(wv[1]))));
      }
    }
    __syncthreads();
  }
}

extern "C" void kernel_launch(void* const* d_in, const int* in_sizes, int n_in,
                              void* d_out, int out_size, void* d_ws, size_t ws_size,
                              hipStream_t stream) {
  const float* x  = (const float*)d_in[0];
  const float* A  = (const float*)d_in[1];
  const float* W1 = (const float*)d_in[2];
  const float* g1 = (const float*)d_in[3];
  const float* b1 = (const float*)d_in[4];
  const float* W2 = (const float*)d_in[5];
  const float* g2 = (const float*)d_in[6];
  const float* b2 = (const float*)d_in[7];
  const float* Wp = (const float*)d_in[8];
  const float* bp = (const float*)d_in[9];
  float* out = (float*)d_out;
  const int B = in_sizes[0] / 225;
  ke5<<<dim3(512), dim3(512), 0, stream>>>(x, A, W1, g1, b1, W2, g2, b2, Wp, bp, out, B);
}